// Round 2
// baseline (387.545 us; speedup 1.0000x reference)
//
#include <hip/hip_runtime.h>

typedef unsigned short ushort_t;
typedef __attribute__((ext_vector_type(4))) unsigned short bfx4;
typedef __attribute__((ext_vector_type(8))) unsigned short bfx8;
typedef __attribute__((ext_vector_type(8))) short sfx8;
typedef __attribute__((ext_vector_type(4))) float fx4;

#define SEG   48
#define ABLK  256
#define SPLIT 4
#define APS   (ABLK / SPLIT)   // 64 phase-A segments per phase-B sub-block

__device__ __forceinline__ float bf2f(unsigned short u){
  unsigned int x = ((unsigned int)u) << 16;
  float f; __builtin_memcpy(&f, &x, 4); return f;
}
__device__ __forceinline__ unsigned short f2bf(float f){
  unsigned int x; __builtin_memcpy(&x, &f, 4);
  x += 0x7fffu + ((x >> 16) & 1u);
  return (unsigned short)(x >> 16);
}

// ---------------- one-off: pack W_so into bf16 MFMA-B-fragment order
// wpk[(((nt*5+ks)*64 + lane)*8 + j] = wso[(nt*16+mrow)*153 + ks*32+quad*8+j] (0 if k>=153)
__global__ void k_pack(const float* __restrict__ wso, ushort_t* __restrict__ wpk)
{
  int idx = blockIdx.x * 256 + threadIdx.x;
  if (idx >= 8*5*64*8) return;
  int j    = idx & 7;
  int lane = (idx >> 3) & 63;
  int ks   = (idx >> 9) % 5;
  int nt   = idx / 2560;
  int mrow = lane & 15, quad = lane >> 4;
  int o = nt*16 + mrow;
  int k = ks*32 + quad*8 + j;
  float v = (k < 153) ? wso[o*153 + k] : 0.f;
  wpk[idx] = f2bf(v);
}

// ---------------- old atomic path (ws-size fallback only)
// Factorized: sums[row][0..8] += frames[e][0..8]; sums[row][9] += 1
__global__ void k_edge(const int* __restrict__ ei, const float* __restrict__ frames,
                       float* __restrict__ sums, int E)
{
  int e = blockIdx.x * 256 + threadIdx.x;
  if (e >= E) return;
  int row = ei[e];
  const float* fp = frames + (size_t)e * 9;
  float F[9];
  __builtin_memcpy(F, fp, 36);
  float* sp = sums + (size_t)row * 10;
  #pragma unroll
  for (int t = 0; t < 9; t++) atomicAdd(&sp[t], F[t]);
  atomicAdd(&sp[9], 1.0f);
}

// ---------------- Phase A: bin packed (e<<7 | row&127) by row>>7 into per-(ablock,bin) segments
__global__ __launch_bounds__(256) void k_binA(const int* __restrict__ ei,
                                              const float* __restrict__ frames,
                                              int* __restrict__ counts, int* __restrict__ ids,
                                              float* __restrict__ sums, int E, int NB, int EPB)
{
  __shared__ int smc[512];                  // NB <= 512 bin counters
  const int ablk = blockIdx.x, tid = threadIdx.x;
  for (int b = tid; b < NB; b += 256) smc[b] = 0;
  __syncthreads();
  const int e0 = ablk * EPB;
  for (int i = tid; i < EPB; i += 256){
    int e = e0 + i;
    if (e < E){
      int row = ei[e];
      int bin = row >> 7;
      int r = atomicAdd(&smc[bin], 1);      // ds_add_rtn_u32: rank within (ablk,bin)
      if (r < SEG){
        ids[((size_t)ablk * NB + bin) * SEG + r] = (e << 7) | (row & 127);
      } else {
        // overflow fallback (prob ~1e-8): direct device atomics, correctness-preserving
        const float* fp = frames + (size_t)e * 9;
        float* sp = sums + (size_t)row * 10;
        #pragma unroll
        for (int t = 0; t < 9; t++) atomicAdd(&sp[t], fp[t]);
        atomicAdd(&sp[9], 1.0f);
      }
    }
  }
  __syncthreads();
  for (int b = tid; b < NB; b += 256)
    counts[(size_t)b * ABLK + ablk] = min(smc[b], SEG);   // transposed: coalesced in phase B
}

// ---------------- Phase B: (bin, sp) sub-blocks; LDS Fsum accumulate; write partial tables
__global__ __launch_bounds__(256) void k_binB(const float* __restrict__ frames,
                                              const int* __restrict__ counts,
                                              const int* __restrict__ ids,
                                              float* __restrict__ part, int NB)
{
  __shared__ int   s_pref[APS + 1];
  __shared__ float s_acc[128 * 11];         // stride 11: gcd(11,32)=1 -> spread banks
  const int bin = blockIdx.x >> 2, sp = blockIdx.x & (SPLIT - 1), tid = threadIdx.x;

  if (tid < APS) s_pref[tid + 1] = counts[(size_t)bin * ABLK + sp * APS + tid];
  if (tid == 0) s_pref[0] = 0;
  for (int i = tid; i < 128*11; i += 256) s_acc[i] = 0.f;
  __syncthreads();
  #pragma unroll
  for (int off = 1; off < APS; off <<= 1){
    int v = 0;
    if (tid < APS && tid + 1 > off) v = s_pref[tid + 1 - off];
    __syncthreads();
    if (tid < APS) s_pref[tid + 1] += v;
    __syncthreads();
  }
  const int total = s_pref[APS];

  for (int base = 0; base < total; base += 1024){
    int pk[4];
    // stage 1: locate + load packed ids (4 independent global loads)
    #pragma unroll
    for (int u = 0; u < 4; u++){
      pk[u] = -1;
      int idx = base + u * 256 + tid;
      if (idx < total){
        int lo = 0, hi = APS;                // find seg: pref[seg] <= idx < pref[seg+1]
        while (hi - lo > 1){ int mid = (lo + hi) >> 1; if (s_pref[mid] <= idx) lo = mid; else hi = mid; }
        int slot = idx - s_pref[lo];
        int ablk = sp * APS + lo;
        pk[u] = ids[((size_t)ablk * NB + bin) * SEG + slot];
      }
    }
    // stage 2: issue all frame loads (up to 36 dwords outstanding per thread)
    float F[4][9];
    #pragma unroll
    for (int u = 0; u < 4; u++){
      if (pk[u] >= 0){
        int e = ((unsigned int)pk[u]) >> 7;
        __builtin_memcpy(F[u], frames + (size_t)e * 9, 36);
      }
    }
    // stage 3: accumulate raw frames into per-row Fsum (factorized scatter)
    #pragma unroll
    for (int u = 0; u < 4; u++){
      if (pk[u] >= 0){
        int row7 = pk[u] & 127;
        float* ap = s_acc + row7 * 11;
        #pragma unroll
        for (int t = 0; t < 9; t++) atomicAdd(&ap[t], F[u][t]);  // ds_add_f32 (no rtn)
        atomicAdd(&ap[9], 1.0f);
      }
    }
  }
  __syncthreads();
  float* pb = part + ((size_t)bin * SPLIT + sp) * 1280;
  for (int i = tid; i < 1280; i += 256)
    pb[i] = s_acc[(i / 10) * 11 + (i % 10)];
}

// ---------------- Kernel C: node main pass (vh, vdf, vnorm, Fsum->sh, MFMA s, silu, gate, vrep)
#define NPB 64
#define MS  168   // padded row stride (elements); 168*2B/4 = 84 ≡ 20 mod 32 -> <=2-way LDS conflicts

__global__ __launch_bounds__(256, 4) void k_node(
    const float* __restrict__ scalar, const float* __restrict__ vec,
    const float* __restrict__ sums,   const float* __restrict__ part,
    const float* __restrict__ wdown, const float* __restrict__ wdf,
    const ushort_t* __restrict__ wpk, const float* __restrict__ bso,
    const float* __restrict__ wup,   const float* __restrict__ wg,
    const float* __restrict__ bg,
    float* __restrict__ out0, float* __restrict__ out1, int N)
{
  __shared__ __align__(16) ushort_t sm_merged[NPB * MS];  // phases 0-1: first 12288B hold vec f32
  __shared__ __align__(16) ushort_t sm_vh[NPB * 48];
  __shared__ __align__(16) ushort_t sm_wg[16 * 128];
  __shared__ float  sm_sh[NPB * 10];     // Fsum[9] + cnt per node
  __shared__ float  sm_vdf[NPB * 9];     // vdf[d*3+c] per node
  __shared__ float  sm_wup[256];
  __shared__ float  sm_wd[256];          // transposed: sm_wd[k*16+h] = wdown[h*16+k]
  __shared__ float  sm_wdf[48];
  __shared__ float  sm_bso[128];
  __shared__ float  sm_bg[16];

  const int tid = threadIdx.x;
  const int n0  = blockIdx.x * NPB;

  // ---- phase 0: stage vec (as f32 into sm_merged), wd/wdf, aggregate Fsum partials
  {
    int nv = N - n0; if (nv > NPB) nv = NPB;
    const int valid = nv * 48;
    fx4* scratch = (fx4*)sm_merged;
    for (int idx = tid; idx < NPB*48/4; idx += 256){
      fx4 val = {0.f, 0.f, 0.f, 0.f};
      if (idx*4 < valid) val = *(const fx4*)(vec + (size_t)n0*48 + idx*4);
      scratch[idx] = val;
    }
  }
  sm_wd[tid] = wdown[(tid & 15)*16 + (tid >> 4)];   // transpose on load
  if (tid < 48) sm_wdf[tid] = wdf[tid];
  for (int idx = tid; idx < NPB*10; idx += 256){
    int ni = idx / 10, sl = idx - ni*10;
    int g = n0 + ni;
    float acc = 0.f;
    if (g < N){
      acc = sums[(size_t)g*10 + sl];           // rare overflow-fallback adds (usually 0)
      if (part){
        const float* pb = part + ((size_t)(g >> 7) * SPLIT) * 1280 + (g & 127) * 10 + sl;
        #pragma unroll
        for (int sp = 0; sp < SPLIT; sp++) acc += pb[(size_t)sp * 1280];
      }
    }
    sm_sh[idx] = acc;
  }
  __syncthreads();

  // ---- phase 1: vh (1024 items (ni,h), weight reads broadcast) + vdf (192 items)
  #pragma unroll
  for (int it = 0; it < 4; it++){
    int idx = tid + it*256;
    int ni = idx >> 4, h = idx & 15;
    const float* sv = (const float*)sm_merged + ni*48;
    float a0 = 0.f, a1 = 0.f, a2 = 0.f;
    #pragma unroll
    for (int k = 0; k < 16; k++){
      float w = sm_wd[k*16 + h];
      a0 += sv[k*3+0]*w; a1 += sv[k*3+1]*w; a2 += sv[k*3+2]*w;
    }
    sm_vh[ni*48 +  0 + h] = f2bf(a0);
    sm_vh[ni*48 + 16 + h] = f2bf(a1);
    sm_vh[ni*48 + 32 + h] = f2bf(a2);
  }
  if (tid < NPB*3){
    const int ni = tid / 3, d = tid - ni*3;
    const float* sv = (const float*)sm_merged + ni*48;
    float c0 = 0.f, c1 = 0.f, c2 = 0.f;
    #pragma unroll
    for (int k = 0; k < 16; k++){
      float v = sv[k*3 + d];
      c0 += v * sm_wdf[ 0 + k];
      c1 += v * sm_wdf[16 + k];
      c2 += v * sm_wdf[32 + k];
    }
    sm_vdf[ni*9 + d*3 + 0] = c0;
    sm_vdf[ni*9 + d*3 + 1] = c1;
    sm_vdf[ni*9 + d*3 + 2] = c2;
  }
  __syncthreads();

  // ---- phase 2: assemble merged row (scalar | vnorm | sh | pad), stage small tensors
  for (int idx = tid; idx < NPB*32; idx += 256){
    int ni = idx >> 5, c4 = (idx & 31) * 4;
    int g = n0 + ni;
    if (g < N){
      fx4 x = *(const fx4*)(scalar + (size_t)g*128 + c4);
      bfx4 b; b[0]=f2bf(x[0]); b[1]=f2bf(x[1]); b[2]=f2bf(x[2]); b[3]=f2bf(x[3]);
      *(bfx4*)(sm_merged + ni*MS + c4) = b;
    } else {
      bfx4 b = {0,0,0,0};
      *(bfx4*)(sm_merged + ni*MS + c4) = b;
    }
  }
  #pragma unroll
  for (int it = 0; it < 4; it++){
    int idx = tid + it*256;
    int ni = idx >> 4, h = idx & 15;
    float x0 = bf2f(sm_vh[ni*48 +  0 + h]);
    float x1 = bf2f(sm_vh[ni*48 + 16 + h]);
    float x2 = bf2f(sm_vh[ni*48 + 32 + h]);
    sm_merged[ni*MS + 128 + h] = f2bf(sqrtf(x0*x0 + x1*x1 + x2*x2 + 1e-8f));
  }
  // sh[c*3+i] = (Fsum[i][:] . vdf[:][c]) / max(cnt,1)   (factorized rotation, per node)
  for (int idx = tid; idx < NPB*9; idx += 256){
    int ni = idx / 9, t = idx - ni*9;
    int c = t / 3, i3 = (t - c*3) * 3;
    float cnt = sm_sh[ni*10 + 9];
    float inv = 1.0f / fmaxf(cnt, 1.0f);
    const float* Fs = sm_sh + ni*10;
    const float* vd = sm_vdf + ni*9;
    float val = Fs[i3+0]*vd[0*3+c] + Fs[i3+1]*vd[1*3+c] + Fs[i3+2]*vd[2*3+c];
    sm_merged[ni*MS + 144 + t] = f2bf(val * inv);
  }
  for (int idx = tid; idx < NPB*7; idx += 256){
    int ni = idx / 7, t = idx - ni*7;
    sm_merged[ni*MS + 153 + t] = 0;            // zero MFMA pad cols 153..159
  }
  for (int idx = tid; idx < 2048; idx += 256) sm_wg[idx] = f2bf(wg[idx]);
  sm_wup[tid] = wup[tid];
  if (tid < 128) sm_bso[tid] = bso[tid];
  if (tid < 16) sm_bg[tid] = bg[tid];
  __syncthreads();

  // ---- phase 3: MFMA (B-fragments streamed from prepacked global, L2-resident)
  const int lane = tid & 63;
  const int wv   = tid >> 6;
  const int mrow = lane & 15;
  const int quad = lane >> 4;
  sfx8 afr[5];
  {
    const ushort_t* ab = sm_merged + (wv*16 + mrow)*MS + quad*8;
    #pragma unroll
    for (int ks = 0; ks < 5; ks++) afr[ks] = *(const sfx8*)(ab + ks*32);
  }
  const ushort_t* wb = wpk + lane*8;
  #pragma unroll
  for (int nt = 0; nt < 8; nt++){
    fx4 acc = {0.f, 0.f, 0.f, 0.f};
    #pragma unroll
    for (int ks = 0; ks < 5; ks++){
      sfx8 bfr = *(const sfx8*)(wb + (size_t)(nt*5 + ks)*64*8);
      acc = __builtin_amdgcn_mfma_f32_16x16x32_bf16(afr[ks], bfr, acc, 0, 0, 0);
    }
    const int o = nt*16 + mrow;
    const float bso_v = sm_bso[o];
    #pragma unroll
    for (int r = 0; r < 4; r++){
      int m = quad*4 + r;
      int g = n0 + wv*16 + m;
      float s = acc[r] + bso_v;
      float sact = s / (1.f + __expf(-s));
      if (g < N) out0[(size_t)g*128 + o] = sact;
      sm_merged[(wv*16 + m)*MS + o] = f2bf(sact);
    }
  }
  __syncthreads();

  // ---- phase 4: gate + vrep
  for (int it = 0; it < 4; it++){
    int widx = tid + it*256;
    int ni = widx >> 4, o16 = widx & 15;
    int g = n0 + ni;
    float acc = sm_bg[o16];
    #pragma unroll
    for (int j8 = 0; j8 < 16; j8++){
      bfx8 svv = *(const bfx8*)(sm_merged + ni*MS + j8*8);
      bfx8 wv8 = *(const bfx8*)(sm_wg + o16*128 + j8*8);
      #pragma unroll
      for (int t = 0; t < 8; t++) acc += bf2f(svv[t]) * bf2f(wv8[t]);
    }
    float sig = 1.f / (1.f + __expf(-acc));
    #pragma unroll
    for (int d = 0; d < 3; d++){
      float r = 0.f;
      #pragma unroll
      for (int h = 0; h < 16; h++)
        r += bf2f(sm_vh[ni*48 + d*16 + h]) * sm_wup[o16*16 + h];
      if (g < N) out1[((size_t)g*16 + o16)*3 + d] = r * sig;
    }
  }
}

extern "C" void kernel_launch(void* const* d_in, const int* in_sizes, int n_in,
                              void* d_out, int out_size, void* d_ws, size_t ws_size,
                              hipStream_t stream)
{
  const float* scalar = (const float*)d_in[0];
  const float* vec    = (const float*)d_in[1];
  const int*   ei     = (const int*)d_in[2];
  const float* frames = (const float*)d_in[3];
  const float* wdown  = (const float*)d_in[4];
  const float* wdf    = (const float*)d_in[5];
  const float* wso    = (const float*)d_in[6];
  const float* bso    = (const float*)d_in[7];
  const float* wup    = (const float*)d_in[8];
  const float* wg     = (const float*)d_in[9];
  const float* bg     = (const float*)d_in[10];

  const int N = in_sizes[0] / 128;
  const int E = in_sizes[2] / 2;
  const int NB  = (N + 127) >> 7;                 // 391 bins of 128 nodes
  const int EPB = (E + ABLK - 1) / ABLK;          // edges per phase-A block

  char* wp = (char*)d_ws;
  float*    sums  = (float*)wp;                    wp += (size_t)N * 10 * sizeof(float);
  ushort_t* wpk   = (ushort_t*)wp;                 wp += (size_t)8*5*64*8 * sizeof(ushort_t);
  int*      counts= (int*)wp;                      wp += (size_t)NB * ABLK * sizeof(int);
  int*      ids   = (int*)wp;                      wp += (size_t)ABLK * NB * SEG * sizeof(int);
  float*    part  = (float*)wp;                    wp += (size_t)NB * SPLIT * 1280 * sizeof(float);
  const size_t ws_needed = (size_t)(wp - (char*)d_ws);

  float* out0 = (float*)d_out;                    // silu(s): N x 128 f32
  float* out1 = out0 + (size_t)N * 128;           // vrep:    N x 16 x 3 f32

  const bool binned = (ws_size >= ws_needed) && (NB <= 512) && (E < (1 << 25));

  (void)hipMemsetAsync(sums, 0, (size_t)N * 10 * sizeof(float), stream);
  k_pack<<<(8*5*64*8 + 255)/256, 256, 0, stream>>>(wso, wpk);
  if (binned){
    k_binA<<<ABLK, 256, 0, stream>>>(ei, frames, counts, ids, sums, E, NB, EPB);
    k_binB<<<NB * SPLIT, 256, 0, stream>>>(frames, counts, ids, part, NB);
  } else {
    k_edge<<<(E + 255) / 256, 256, 0, stream>>>(ei, frames, sums, E);
  }
  k_node<<<(N + NPB - 1) / NPB, 256, 0, stream>>>(scalar, vec, sums, binned ? part : nullptr,
                                                  wdown, wdf, wpk, bso, wup, wg, bg, out0, out1, N);
}

// Round 3
// 319.120 us; speedup vs baseline: 1.2144x; 1.2144x over previous
//
#include <hip/hip_runtime.h>

typedef unsigned short ushort_t;
typedef __attribute__((ext_vector_type(4))) unsigned short bfx4;
typedef __attribute__((ext_vector_type(8))) unsigned short bfx8;
typedef __attribute__((ext_vector_type(8))) short sfx8;
typedef __attribute__((ext_vector_type(4))) float fx4;

#define SEG   48
#define ABLK  256
#define SPLIT 4
#define APS   (ABLK / SPLIT)   // 64 phase-A segments per phase-B sub-block

__device__ __forceinline__ float bf2f(unsigned short u){
  unsigned int x = ((unsigned int)u) << 16;
  float f; __builtin_memcpy(&f, &x, 4); return f;
}
__device__ __forceinline__ unsigned short f2bf(float f){
  unsigned int x; __builtin_memcpy(&x, &f, 4);
  x += 0x7fffu + ((x >> 16) & 1u);
  return (unsigned short)(x >> 16);
}

// ---------------- one-off: pack W_so into bf16 MFMA-B-fragment order
// wpk[(((nt*5+ks)*64 + lane)*8 + j] = wso[(nt*16+mrow)*153 + ks*32+quad*8+j] (0 if k>=153)
__global__ void k_pack(const float* __restrict__ wso, ushort_t* __restrict__ wpk)
{
  int idx = blockIdx.x * 256 + threadIdx.x;
  if (idx >= 8*5*64*8) return;
  int j    = idx & 7;
  int lane = (idx >> 3) & 63;
  int ks   = (idx >> 9) % 5;
  int nt   = idx / 2560;
  int mrow = lane & 15, quad = lane >> 4;
  int o = nt*16 + mrow;
  int k = ks*32 + quad*8 + j;
  float v = (k < 153) ? wso[o*153 + k] : 0.f;
  wpk[idx] = f2bf(v);
}

// ---------------- old atomic path (ws-size fallback only)
// Factorized: sums[row][0..8] += frames[e][0..8]; sums[row][9] += 1
__global__ void k_edge(const int* __restrict__ ei, const float* __restrict__ frames,
                       float* __restrict__ sums, int E)
{
  int e = blockIdx.x * 256 + threadIdx.x;
  if (e >= E) return;
  int row = ei[e];
  const float* fp = frames + (size_t)e * 9;
  float F[9];
  __builtin_memcpy(F, fp, 36);
  float* sp = sums + (size_t)row * 10;
  #pragma unroll
  for (int t = 0; t < 9; t++) atomicAdd(&sp[t], F[t]);
  atomicAdd(&sp[9], 1.0f);
}

// ---------------- Phase A: bin packed (e<<7 | row&127) by row>>7 into per-(ablock,bin) segments
__global__ __launch_bounds__(256) void k_binA(const int* __restrict__ ei,
                                              const float* __restrict__ frames,
                                              int* __restrict__ counts, int* __restrict__ ids,
                                              float* __restrict__ sums, int E, int NB, int EPB)
{
  __shared__ int smc[512];                  // NB <= 512 bin counters
  const int ablk = blockIdx.x, tid = threadIdx.x;
  for (int b = tid; b < NB; b += 256) smc[b] = 0;
  __syncthreads();
  const int e0 = ablk * EPB;
  for (int i = tid; i < EPB; i += 256){
    int e = e0 + i;
    if (e < E){
      int row = ei[e];
      int bin = row >> 7;
      int r = atomicAdd(&smc[bin], 1);      // ds_add_rtn_u32: rank within (ablk,bin)
      if (r < SEG){
        ids[((size_t)ablk * NB + bin) * SEG + r] = (e << 7) | (row & 127);
      } else {
        // overflow fallback (prob ~1e-8): direct device atomics, correctness-preserving
        const float* fp = frames + (size_t)e * 9;
        float* sp = sums + (size_t)row * 10;
        #pragma unroll
        for (int t = 0; t < 9; t++) atomicAdd(&sp[t], fp[t]);
        atomicAdd(&sp[9], 1.0f);
      }
    }
  }
  __syncthreads();
  for (int b = tid; b < NB; b += 256)
    counts[(size_t)b * ABLK + ablk] = min(smc[b], SEG);   // transposed: coalesced in phase B
}

// ---------------- Phase B: (bin, sp) sub-blocks; LDS Fsum accumulate; write partial tables
__global__ __launch_bounds__(256) void k_binB(const float* __restrict__ frames,
                                              const int* __restrict__ counts,
                                              const int* __restrict__ ids,
                                              float* __restrict__ part, int NB)
{
  __shared__ int   s_pref[APS + 1];
  __shared__ float s_acc[128 * 11];         // stride 11: gcd(11,32)=1 -> spread banks
  const int bin = blockIdx.x >> 2, sp = blockIdx.x & (SPLIT - 1), tid = threadIdx.x;

  if (tid < APS) s_pref[tid + 1] = counts[(size_t)bin * ABLK + sp * APS + tid];
  if (tid == 0) s_pref[0] = 0;
  for (int i = tid; i < 128*11; i += 256) s_acc[i] = 0.f;
  __syncthreads();
  #pragma unroll
  for (int off = 1; off < APS; off <<= 1){
    int v = 0;
    if (tid < APS && tid + 1 > off) v = s_pref[tid + 1 - off];
    __syncthreads();
    if (tid < APS) s_pref[tid + 1] += v;
    __syncthreads();
  }
  const int total = s_pref[APS];

  for (int base = 0; base < total; base += 1024){
    int pk[4];
    // stage 1: locate + load packed ids (4 independent global loads)
    #pragma unroll
    for (int u = 0; u < 4; u++){
      pk[u] = -1;
      int idx = base + u * 256 + tid;
      if (idx < total){
        int lo = 0, hi = APS;                // find seg: pref[seg] <= idx < pref[seg+1]
        while (hi - lo > 1){ int mid = (lo + hi) >> 1; if (s_pref[mid] <= idx) lo = mid; else hi = mid; }
        int slot = idx - s_pref[lo];
        int ablk = sp * APS + lo;
        pk[u] = ids[((size_t)ablk * NB + bin) * SEG + slot];
      }
    }
    // stage 2: issue all frame loads (up to 36 dwords outstanding per thread)
    float F[4][9];
    #pragma unroll
    for (int u = 0; u < 4; u++){
      if (pk[u] >= 0){
        int e = ((unsigned int)pk[u]) >> 7;
        __builtin_memcpy(F[u], frames + (size_t)e * 9, 36);
      }
    }
    // stage 3: accumulate raw frames into per-row Fsum (factorized scatter)
    #pragma unroll
    for (int u = 0; u < 4; u++){
      if (pk[u] >= 0){
        int row7 = pk[u] & 127;
        float* ap = s_acc + row7 * 11;
        #pragma unroll
        for (int t = 0; t < 9; t++) atomicAdd(&ap[t], F[u][t]);  // ds_add_f32 (no rtn)
        atomicAdd(&ap[9], 1.0f);
      }
    }
  }
  __syncthreads();
  float* pb = part + ((size_t)bin * SPLIT + sp) * 1280;
  for (int i = tid; i < 1280; i += 256)
    pb[i] = s_acc[(i / 10) * 11 + (i % 10)];
}

// ---------------- Kernel C: node main pass (vh, vdf, vnorm, Fsum->sh, MFMA s, silu, gate, vrep)
#define NPB 64
#define MS  168   // padded row stride (elements); 168*2B/4 = 84 ≡ 20 mod 32 -> <=2-way LDS conflicts
#define WGS 136   // sm_wg row stride (shorts): 272B, 16B-aligned, 68 dw ≡ 4 mod 32 -> <=2-way

__global__ __launch_bounds__(256) void k_node(
    const float* __restrict__ scalar, const float* __restrict__ vec,
    const float* __restrict__ sums,   const float* __restrict__ part,
    const float* __restrict__ wdown, const float* __restrict__ wdf,
    const ushort_t* __restrict__ wpk, const float* __restrict__ bso,
    const float* __restrict__ wup,   const float* __restrict__ wg,
    const float* __restrict__ bg,
    float* __restrict__ out0, float* __restrict__ out1, int N)
{
  __shared__ __align__(16) ushort_t sm_merged[NPB * MS];  // phases 0-1: first 12288B hold vec f32
  __shared__ __align__(16) ushort_t sm_vh[NPB * 48];
  __shared__ __align__(16) ushort_t sm_wg[16 * WGS];
  __shared__ float  sm_sh[NPB * 10];     // Fsum[9] + cnt per node
  __shared__ float  sm_vdf[NPB * 9];     // vdf[d*3+c] per node
  __shared__ float  sm_wup[256];
  __shared__ float  sm_wd[256];          // transposed: sm_wd[k*16+h] = wdown[h*16+k]
  __shared__ float  sm_wdf[48];
  __shared__ float  sm_bso[128];
  __shared__ float  sm_bg[16];

  const int tid = threadIdx.x;
  const int n0  = blockIdx.x * NPB;

  // ---- phase 0: stage vec (as f32 into sm_merged), wd/wdf, aggregate Fsum partials
  {
    int nv = N - n0; if (nv > NPB) nv = NPB;
    const int valid = nv * 48;
    fx4* scratch = (fx4*)sm_merged;
    for (int idx = tid; idx < NPB*48/4; idx += 256){
      fx4 val = {0.f, 0.f, 0.f, 0.f};
      if (idx*4 < valid) val = *(const fx4*)(vec + (size_t)n0*48 + idx*4);
      scratch[idx] = val;
    }
  }
  sm_wd[tid] = wdown[(tid & 15)*16 + (tid >> 4)];   // transpose on load
  if (tid < 48) sm_wdf[tid] = wdf[tid];
  for (int idx = tid; idx < NPB*10; idx += 256){
    int ni = idx / 10, sl = idx - ni*10;
    int g = n0 + ni;
    float acc = 0.f;
    if (g < N){
      acc = sums[(size_t)g*10 + sl];           // rare overflow-fallback adds (usually 0)
      if (part){
        const float* pb = part + ((size_t)(g >> 7) * SPLIT) * 1280 + (g & 127) * 10 + sl;
        #pragma unroll
        for (int sp = 0; sp < SPLIT; sp++) acc += pb[(size_t)sp * 1280];
      }
    }
    sm_sh[idx] = acc;
  }
  __syncthreads();

  // ---- phase 1: vh (1024 items (ni,h), weight reads broadcast) + vdf (192 items)
  #pragma unroll
  for (int it = 0; it < 4; it++){
    int idx = tid + it*256;
    int ni = idx >> 4, h = idx & 15;
    const float* sv = (const float*)sm_merged + ni*48;
    float a0 = 0.f, a1 = 0.f, a2 = 0.f;
    #pragma unroll
    for (int k = 0; k < 16; k++){
      float w = sm_wd[k*16 + h];
      a0 += sv[k*3+0]*w; a1 += sv[k*3+1]*w; a2 += sv[k*3+2]*w;
    }
    sm_vh[ni*48 +  0 + h] = f2bf(a0);
    sm_vh[ni*48 + 16 + h] = f2bf(a1);
    sm_vh[ni*48 + 32 + h] = f2bf(a2);
  }
  if (tid < NPB*3){
    const int ni = tid / 3, d = tid - ni*3;
    const float* sv = (const float*)sm_merged + ni*48;
    float c0 = 0.f, c1 = 0.f, c2 = 0.f;
    #pragma unroll
    for (int k = 0; k < 16; k++){
      float v = sv[k*3 + d];
      c0 += v * sm_wdf[ 0 + k];
      c1 += v * sm_wdf[16 + k];
      c2 += v * sm_wdf[32 + k];
    }
    sm_vdf[ni*9 + d*3 + 0] = c0;
    sm_vdf[ni*9 + d*3 + 1] = c1;
    sm_vdf[ni*9 + d*3 + 2] = c2;
  }
  __syncthreads();

  // ---- phase 2: assemble merged row (scalar | vnorm | sh | pad), stage small tensors
  for (int idx = tid; idx < NPB*32; idx += 256){
    int ni = idx >> 5, c4 = (idx & 31) * 4;
    int g = n0 + ni;
    if (g < N){
      fx4 x = *(const fx4*)(scalar + (size_t)g*128 + c4);
      bfx4 b; b[0]=f2bf(x[0]); b[1]=f2bf(x[1]); b[2]=f2bf(x[2]); b[3]=f2bf(x[3]);
      *(bfx4*)(sm_merged + ni*MS + c4) = b;
    } else {
      bfx4 b = {0,0,0,0};
      *(bfx4*)(sm_merged + ni*MS + c4) = b;
    }
  }
  #pragma unroll
  for (int it = 0; it < 4; it++){
    int idx = tid + it*256;
    int ni = idx >> 4, h = idx & 15;
    float x0 = bf2f(sm_vh[ni*48 +  0 + h]);
    float x1 = bf2f(sm_vh[ni*48 + 16 + h]);
    float x2 = bf2f(sm_vh[ni*48 + 32 + h]);
    sm_merged[ni*MS + 128 + h] = f2bf(sqrtf(x0*x0 + x1*x1 + x2*x2 + 1e-8f));
  }
  // sh[c*3+i] = (Fsum[i][:] . vdf[:][c]) / max(cnt,1)   (factorized rotation, per node)
  for (int idx = tid; idx < NPB*9; idx += 256){
    int ni = idx / 9, t = idx - ni*9;
    int c = t / 3, i3 = (t - c*3) * 3;
    float cnt = sm_sh[ni*10 + 9];
    float inv = 1.0f / fmaxf(cnt, 1.0f);
    const float* Fs = sm_sh + ni*10;
    const float* vd = sm_vdf + ni*9;
    float val = Fs[i3+0]*vd[0*3+c] + Fs[i3+1]*vd[1*3+c] + Fs[i3+2]*vd[2*3+c];
    sm_merged[ni*MS + 144 + t] = f2bf(val * inv);
  }
  for (int idx = tid; idx < NPB*7; idx += 256){
    int ni = idx / 7, t = idx - ni*7;
    sm_merged[ni*MS + 153 + t] = 0;            // zero MFMA pad cols 153..159
  }
  for (int idx = tid; idx < 2048; idx += 256)
    sm_wg[(idx >> 7)*WGS + (idx & 127)] = f2bf(wg[idx]);
  sm_wup[tid] = wup[tid];
  if (tid < 128) sm_bso[tid] = bso[tid];
  if (tid < 16) sm_bg[tid] = bg[tid];
  __syncthreads();

  // ---- phase 3: MFMA (B-fragments streamed from prepacked global, L2-resident)
  const int lane = tid & 63;
  const int wv   = tid >> 6;
  const int mrow = lane & 15;
  const int quad = lane >> 4;
  sfx8 afr[5];
  {
    const ushort_t* ab = sm_merged + (wv*16 + mrow)*MS + quad*8;
    #pragma unroll
    for (int ks = 0; ks < 5; ks++) afr[ks] = *(const sfx8*)(ab + ks*32);
  }
  const ushort_t* wb = wpk + lane*8;
  #pragma unroll
  for (int nt = 0; nt < 8; nt++){
    fx4 acc = {0.f, 0.f, 0.f, 0.f};
    #pragma unroll
    for (int ks = 0; ks < 5; ks++){
      sfx8 bfr = *(const sfx8*)(wb + (size_t)(nt*5 + ks)*64*8);
      acc = __builtin_amdgcn_mfma_f32_16x16x32_bf16(afr[ks], bfr, acc, 0, 0, 0);
    }
    const int o = nt*16 + mrow;
    const float bso_v = sm_bso[o];
    #pragma unroll
    for (int r = 0; r < 4; r++){
      int m = quad*4 + r;
      int g = n0 + wv*16 + m;
      float s = acc[r] + bso_v;
      float sact = s / (1.f + __expf(-s));
      if (g < N) out0[(size_t)g*128 + o] = sact;
      sm_merged[(wv*16 + m)*MS + o] = f2bf(sact);
    }
  }
  __syncthreads();

  // ---- phase 4: gate + vrep
  for (int it = 0; it < 4; it++){
    int widx = tid + it*256;
    int ni = widx >> 4, o16 = widx & 15;
    int g = n0 + ni;
    float acc = sm_bg[o16];
    #pragma unroll
    for (int j8 = 0; j8 < 16; j8++){
      bfx8 svv = *(const bfx8*)(sm_merged + ni*MS + j8*8);
      bfx8 wv8 = *(const bfx8*)(sm_wg + o16*WGS + j8*8);
      #pragma unroll
      for (int t = 0; t < 8; t++) acc += bf2f(svv[t]) * bf2f(wv8[t]);
    }
    float sig = 1.f / (1.f + __expf(-acc));
    #pragma unroll
    for (int d = 0; d < 3; d++){
      float r = 0.f;
      #pragma unroll
      for (int h = 0; h < 16; h++)
        r += bf2f(sm_vh[ni*48 + d*16 + h]) * sm_wup[o16*16 + h];
      if (g < N) out1[((size_t)g*16 + o16)*3 + d] = r * sig;
    }
  }
}

extern "C" void kernel_launch(void* const* d_in, const int* in_sizes, int n_in,
                              void* d_out, int out_size, void* d_ws, size_t ws_size,
                              hipStream_t stream)
{
  const float* scalar = (const float*)d_in[0];
  const float* vec    = (const float*)d_in[1];
  const int*   ei     = (const int*)d_in[2];
  const float* frames = (const float*)d_in[3];
  const float* wdown  = (const float*)d_in[4];
  const float* wdf    = (const float*)d_in[5];
  const float* wso    = (const float*)d_in[6];
  const float* bso    = (const float*)d_in[7];
  const float* wup    = (const float*)d_in[8];
  const float* wg     = (const float*)d_in[9];
  const float* bg     = (const float*)d_in[10];

  const int N = in_sizes[0] / 128;
  const int E = in_sizes[2] / 2;
  const int NB  = (N + 127) >> 7;                 // 391 bins of 128 nodes
  const int EPB = (E + ABLK - 1) / ABLK;          // edges per phase-A block

  char* wp = (char*)d_ws;
  float*    sums  = (float*)wp;                    wp += (size_t)N * 10 * sizeof(float);
  ushort_t* wpk   = (ushort_t*)wp;                 wp += (size_t)8*5*64*8 * sizeof(ushort_t);
  int*      counts= (int*)wp;                      wp += (size_t)NB * ABLK * sizeof(int);
  int*      ids   = (int*)wp;                      wp += (size_t)ABLK * NB * SEG * sizeof(int);
  float*    part  = (float*)wp;                    wp += (size_t)NB * SPLIT * 1280 * sizeof(float);
  const size_t ws_needed = (size_t)(wp - (char*)d_ws);

  float* out0 = (float*)d_out;                    // silu(s): N x 128 f32
  float* out1 = out0 + (size_t)N * 128;           // vrep:    N x 16 x 3 f32

  const bool binned = (ws_size >= ws_needed) && (NB <= 512) && (E < (1 << 25));

  (void)hipMemsetAsync(sums, 0, (size_t)N * 10 * sizeof(float), stream);
  k_pack<<<(8*5*64*8 + 255)/256, 256, 0, stream>>>(wso, wpk);
  if (binned){
    k_binA<<<ABLK, 256, 0, stream>>>(ei, frames, counts, ids, sums, E, NB, EPB);
    k_binB<<<NB * SPLIT, 256, 0, stream>>>(frames, counts, ids, part, NB);
  } else {
    k_edge<<<(E + 255) / 256, 256, 0, stream>>>(ei, frames, sums, E);
  }
  k_node<<<(N + NPB - 1) / NPB, 256, 0, stream>>>(scalar, vec, sums, binned ? part : nullptr,
                                                  wdown, wdf, wpk, bso, wup, wg, bg, out0, out1, N);
}